// Round 1
// baseline (418.779 us; speedup 1.0000x reference)
//
#include <hip/hip_runtime.h>

// out[b,c,Y,X] = sum_{dy,dx in [-4,4]} corr[b,(dy+4)*9+(dx+4),Y-dy,X-dx] * feat[b,c,Y-dy,X-dx]
// zero-padding semantics at borders.

#define RR 4
#define DD 9
#define D2 81
#define Bn 16
#define Cn 256
#define Hn 96
#define Wn 96
#define HWn (Hn*Wn)

#define NC 8              // channels per block
#define TY 8              // output rows per block
#define TXR 4             // x outputs per thread
#define NTX (Wn/TXR)      // 24 thread x-positions
#define NTH (NTX*TY)      // 192 threads per block
#define LROWS (TY+2*RR)   // 16 staged rows (with halo)
#define LW (Wn+2*RR)      // 104 padded width

__global__ __launch_bounds__(NTH)
void corrT_kernel(const float* __restrict__ corr,
                  const float* __restrict__ feat,
                  float* __restrict__ out)
{
    __shared__ float lds[NC * LROWS * LW];   // 8*16*104*4 = 53248 B

    const int bid = blockIdx.x;
    const int cg  = bid % (Cn / NC);                 // channel-group fastest: corr L2 reuse
    const int yb  = (bid / (Cn / NC)) % (Hn / TY);
    const int b   = bid / ((Cn / NC) * (Hn / TY));
    const int y0  = yb * TY;
    const int c0  = cg * NC;
    const int tid = threadIdx.x;

    // ---- stage feat tile into zero-padded LDS (halo handled here, once) ----
    const float* featb = feat + (size_t)(b * Cn + c0) * HWn;
    #pragma unroll
    for (int it = 0; it < (NC * LROWS * NTX) / NTH; ++it) {   // 16 iters
        int lin = it * NTH + tid;
        int xq  = lin % NTX;
        int row = (lin / NTX) % LROWS;
        int c   = lin / (NTX * LROWS);
        int gy  = y0 - RR + row;
        float4 v = make_float4(0.f, 0.f, 0.f, 0.f);
        if (gy >= 0 && gy < Hn)
            v = *reinterpret_cast<const float4*>(&featb[(size_t)c * HWn + gy * Wn + xq * 4]);
        *reinterpret_cast<float4*>(&lds[(c * LROWS + row) * LW + RR + xq * 4]) = v;
    }
    if (tid < NC * LROWS) {   // zero the 4-float left/right pads of each row
        float4 z = make_float4(0.f, 0.f, 0.f, 0.f);
        *reinterpret_cast<float4*>(&lds[tid * LW]) = z;
        *reinterpret_cast<float4*>(&lds[tid * LW + RR + Wn]) = z;
    }
    __syncthreads();

    const int tx = tid % NTX;
    const int ty = tid / NTX;
    const int y  = y0 + ty;
    const int x0 = tx * TXR;

    const float* corrb = corr + (size_t)b * D2 * HWn;   // uniform -> SGPR base

    // clamped source-x offsets (thread-constant); OOB positions multiply zero pads
    int sxo[12];
    #pragma unroll
    for (int t = 0; t < 12; ++t) {
        int sx = x0 - RR + t;
        sxo[t] = min(max(sx, 0), Wn - 1);
    }

    float acc[NC][TXR];
    #pragma unroll
    for (int c = 0; c < NC; ++c)
        #pragma unroll
        for (int j = 0; j < TXR; ++j)
            acc[c][j] = 0.f;

    #pragma unroll 1
    for (int kdy = 0; kdy < DD; ++kdy) {
        int sy  = y + RR - kdy;                  // source row
        int syc = min(max(sy, 0), Hn - 1);       // clamped (values masked by zero LDS rows)
        int rb  = (kdy * DD) * HWn + syc * Wn;   // 32-bit offset

        // 36 corr values in registers, shared by all 8 channels
        float cv[DD][TXR];
        #pragma unroll
        for (int kdx = 0; kdx < DD; ++kdx)
            #pragma unroll
            for (int j = 0; j < TXR; ++j)
                cv[kdx][j] = corrb[rb + kdx * HWn + sxo[j + 8 - kdx]];

        int r = ty + 2 * RR - kdy;               // LDS row (always in tile)
        #pragma unroll
        for (int c = 0; c < NC; ++c) {
            const float4* fp = reinterpret_cast<const float4*>(&lds[(c * LROWS + r) * LW + x0]);
            float4 fa = fp[0], fb4 = fp[1], fc4 = fp[2];
            float f[12] = {fa.x, fa.y, fa.z, fa.w,
                           fb4.x, fb4.y, fb4.z, fb4.w,
                           fc4.x, fc4.y, fc4.z, fc4.w};
            #pragma unroll
            for (int kdx = 0; kdx < DD; ++kdx)
                #pragma unroll
                for (int j = 0; j < TXR; ++j)
                    acc[c][j] = fmaf(cv[kdx][j], f[j + 8 - kdx], acc[c][j]);
        }
    }

    float* outb = out + (size_t)(b * Cn + c0) * HWn + y * Wn + x0;
    #pragma unroll
    for (int c = 0; c < NC; ++c) {
        float4 v = make_float4(acc[c][0], acc[c][1], acc[c][2], acc[c][3]);
        *reinterpret_cast<float4*>(&outb[(size_t)c * HWn]) = v;
    }
}

extern "C" void kernel_launch(void* const* d_in, const int* in_sizes, int n_in,
                              void* d_out, int out_size, void* d_ws, size_t ws_size,
                              hipStream_t stream)
{
    const float* corr = (const float*)d_in[0];   // [16,81,96,96]
    const float* feat = (const float*)d_in[1];   // [16,256,96,96]
    float* out = (float*)d_out;                  // [16,256,96,96]

    const int grid = Bn * (Cn / NC) * (Hn / TY); // 16*32*12 = 6144
    corrT_kernel<<<grid, NTH, 0, stream>>>(corr, feat, out);
}

// Round 2
// 289.049 us; speedup vs baseline: 1.4488x; 1.4488x over previous
//
#include <hip/hip_runtime.h>

// out[b,c,y,x] = sum_{kdy,kdx in [0,9)} corr[b, kdy*9+kdx, y+4-kdy, x+4-kdx] * feat[b,c, y+4-kdy, x+4-kdx]
// (zero padding outside [0,96) in both spatial dims)

#define RR 4
#define DD 9
#define D2 81
#define Bn 16
#define Cn 256
#define Hn 96
#define Wn 96
#define HWn (Hn*Wn)

#define NTX 12            // x-lane groups
#define TXR 8             // x outputs per thread
#define NTC 16            // channel lanes
#define CT  4             // channels per thread
#define NCB (NTC*CT)      // 64 channels per block
#define NCG (Cn/NCB)      // 4 channel groups
#define NTH (NTX*NTC)     // 192 threads
#define LW  104           // padded LDS row width (floats)
#define LW4 (LW/4)        // 26 float4 per row

__global__ __launch_bounds__(NTH, 4)
void corrT2_kernel(const float* __restrict__ corr,
                   const float* __restrict__ feat,
                   float* __restrict__ out)
{
    __shared__ float lds[D2 * LW];          // 81*104*4 = 33696 B

    // XCD-chunked bijective swizzle (grid 6144 % 8 == 0)
    int bid = blockIdx.x;
    int sw  = (bid & 7) * (gridDim.x >> 3) + (bid >> 3);
    int cg  = sw & (NCG - 1);               // channel-group fastest: corr L2 reuse
    int y   = (sw >> 2) % Hn;               // then y: feat row reuse across neighbors
    int b   = sw / (NCG * Hn);

    const int tid = threadIdx.x;
    const float* corrb = corr + (size_t)b * D2 * HWn;

    // ---- stage corr rows into LDS, x-shifted by kdx, zero-padded ----
    // lds[row][col] = corr[b, row, y+4-kdy, col - kdx]  (0 if OOB), row = kdy*9+kdx
    for (int idx = tid; idx < D2 * LW4; idx += NTH) {
        int row = idx / LW4;
        int c4  = idx - row * LW4;
        int kdy = row / DD;
        int kdx = row - kdy * DD;
        int sy  = y + RR - kdy;
        float4 v = make_float4(0.f, 0.f, 0.f, 0.f);
        if (sy >= 0 && sy < Hn) {
            const float* src = corrb + (size_t)row * HWn + sy * Wn;
            int col0 = c4 * 4;
            #pragma unroll
            for (int e = 0; e < 4; ++e) {
                int sx = col0 + e - kdx;
                if (sx >= 0 && sx < Wn) (&v.x)[e] = src[sx];
            }
        }
        *reinterpret_cast<float4*>(&lds[row * LW + c4 * 4]) = v;
    }
    __syncthreads();

    const int tx = tid % NTX;
    const int tc = tid / NTX;
    const int x0 = tx * TXR;
    const int c0 = cg * NCB + tc * CT;

    const float* featb = feat + ((size_t)b * Cn + c0) * HWn;

    float acc[CT][TXR] = {};

    #pragma unroll 1
    for (int kdy = 0; kdy < DD; ++kdy) {
        int sy = y + RR - kdy;
        if (sy < 0 || sy >= Hn) continue;   // uniform per block: whole offset row is zero-padded

        // feat windows: f[c][t] = feat[c0+c, sy, x0-4+t], t in [0,16); OOB -> 0
        float f[CT][16];
        const float* frow = featb + sy * Wn + x0 - RR;
        #pragma unroll
        for (int c = 0; c < CT; ++c) {
            const float* p = frow + (size_t)c * HWn;
            float4 f0 = (tx == 0)       ? make_float4(0,0,0,0) : *reinterpret_cast<const float4*>(p);
            float4 f1 = *reinterpret_cast<const float4*>(p + 4);
            float4 f2 = *reinterpret_cast<const float4*>(p + 8);
            float4 f3 = (tx == NTX - 1) ? make_float4(0,0,0,0) : *reinterpret_cast<const float4*>(p + 12);
            f[c][0]=f0.x;  f[c][1]=f0.y;  f[c][2]=f0.z;  f[c][3]=f0.w;
            f[c][4]=f1.x;  f[c][5]=f1.y;  f[c][6]=f1.z;  f[c][7]=f1.w;
            f[c][8]=f2.x;  f[c][9]=f2.y;  f[c][10]=f2.z; f[c][11]=f2.w;
            f[c][12]=f3.x; f[c][13]=f3.y; f[c][14]=f3.z; f[c][15]=f3.w;
        }

        // cv[j] for output x0+j lives at lds[row][x0+4+j] -> aligned b128 pair, row uniform
        const float4* cvp = reinterpret_cast<const float4*>(lds) + (tx * 2 + 1);
        #pragma unroll
        for (int kdx = 0; kdx < DD; ++kdx) {
            int row = kdy * DD + kdx;
            float4 ca = cvp[row * LW4];
            float4 cb = cvp[row * LW4 + 1];
            float cv[8] = {ca.x, ca.y, ca.z, ca.w, cb.x, cb.y, cb.z, cb.w};
            #pragma unroll
            for (int c = 0; c < CT; ++c)
                #pragma unroll
                for (int j = 0; j < TXR; ++j)
                    acc[c][j] = fmaf(cv[j], f[c][j + 8 - kdx], acc[c][j]);
        }
    }

    float* ob = out + ((size_t)b * Cn + c0) * HWn + (size_t)y * Wn + x0;
    #pragma unroll
    for (int c = 0; c < CT; ++c) {
        *reinterpret_cast<float4*>(ob + (size_t)c * HWn)     = make_float4(acc[c][0], acc[c][1], acc[c][2], acc[c][3]);
        *reinterpret_cast<float4*>(ob + (size_t)c * HWn + 4) = make_float4(acc[c][4], acc[c][5], acc[c][6], acc[c][7]);
    }
}

extern "C" void kernel_launch(void* const* d_in, const int* in_sizes, int n_in,
                              void* d_out, int out_size, void* d_ws, size_t ws_size,
                              hipStream_t stream)
{
    const float* corr = (const float*)d_in[0];   // [16,81,96,96]
    const float* feat = (const float*)d_in[1];   // [16,256,96,96]
    float* out = (float*)d_out;                  // [16,256,96,96]

    const int grid = Bn * Hn * NCG;              // 16*96*4 = 6144
    corrT2_kernel<<<grid, NTH, 0, stream>>>(corr, feat, out);
}

// Round 3
// 262.968 us; speedup vs baseline: 1.5925x; 1.0992x over previous
//
#include <hip/hip_runtime.h>

// out[b,c,y,x] = sum_{kdy,kdx in [0,9)} corr[b, kdy*9+kdx, y+4-kdy, x+4-kdx] * feat[b,c, y+4-kdy, x+4-kdx]
// (zero padding outside [0,96) in both spatial dims)

#define RR 4
#define DD 9
#define D2 81
#define Bn 16
#define Cn 256
#define Hn 96
#define Wn 96
#define HWn (Hn*Wn)

#define NTX 12            // x-lane groups
#define TXR 8             // x outputs per thread
#define NTC 32            // channel lanes
#define CT  2             // channels per thread
#define NCB (NTC*CT)      // 64 channels per block
#define NCG (Cn/NCB)      // 4 channel groups
#define NTH (NTX*NTC)     // 384 threads
#define LW  104           // padded LDS row width (floats)
#define LW4 (LW/4)        // 26 float4 per row

__global__ __launch_bounds__(NTH, 6)
void corrT3_kernel(const float* __restrict__ corr,
                   const float* __restrict__ feat,
                   float* __restrict__ out)
{
    __shared__ float lds[D2 * LW];          // 81*104*4 = 33696 B

    // XCD-chunked bijective swizzle (grid 6144 % 8 == 0)
    int bid = blockIdx.x;
    int sw  = (bid & 7) * (gridDim.x >> 3) + (bid >> 3);
    int cg  = sw & (NCG - 1);               // channel-group fastest: corr L2 reuse
    int y   = (sw >> 2) % Hn;               // then y: feat row reuse across neighbors
    int b   = sw / (NCG * Hn);

    const int tid = threadIdx.x;
    const float* corrb = corr + (size_t)b * D2 * HWn;

    // ---- stage corr rows into LDS, x-shifted by kdx, zero-padded ----
    // lds[row][col] = corr[b, row, y+4-kdy, col - kdx]  (0 if OOB), row = kdy*9+kdx
    for (int idx = tid; idx < D2 * LW4; idx += NTH) {
        int row = idx / LW4;
        int c4  = idx - row * LW4;
        int kdy = row / DD;
        int kdx = row - kdy * DD;
        int sy  = y + RR - kdy;
        float4 v = make_float4(0.f, 0.f, 0.f, 0.f);
        if (sy >= 0 && sy < Hn) {
            const float* src = corrb + (size_t)row * HWn + sy * Wn;
            int col0 = c4 * 4;
            #pragma unroll
            for (int e = 0; e < 4; ++e) {
                int sx = col0 + e - kdx;
                if (sx >= 0 && sx < Wn) (&v.x)[e] = src[sx];
            }
        }
        *reinterpret_cast<float4*>(&lds[row * LW + c4 * 4]) = v;
    }
    __syncthreads();

    const int tx = tid % NTX;
    const int tc = tid / NTX;
    const int x0 = tx * TXR;
    const int c0 = cg * NCB + tc * CT;

    const float* featb = feat + ((size_t)b * Cn + c0) * HWn;

    float acc[CT][TXR] = {};

    // contiguous valid kdy range: sy = y+4-kdy in [0,96)
    const int klo = max(0, y - (Hn - 1 - RR));   // y - 91
    const int khi = min(DD - 1, y + RR);

    #pragma unroll 1
    for (int kdy = klo; kdy <= khi; ++kdy) {
        int sy = y + RR - kdy;

        // feat windows: f[c][t] = feat[c0+c, sy, x0-4+t], t in [0,16); OOB -> 0
        float f[CT][16];
        const float* frow = featb + sy * Wn + x0 - RR;
        #pragma unroll
        for (int c = 0; c < CT; ++c) {
            const float* p = frow + (size_t)c * HWn;
            float4 f0 = (tx == 0)       ? make_float4(0,0,0,0) : *reinterpret_cast<const float4*>(p);
            float4 f1 = *reinterpret_cast<const float4*>(p + 4);
            float4 f2 = *reinterpret_cast<const float4*>(p + 8);
            float4 f3 = (tx == NTX - 1) ? make_float4(0,0,0,0) : *reinterpret_cast<const float4*>(p + 12);
            f[c][0]=f0.x;  f[c][1]=f0.y;  f[c][2]=f0.z;  f[c][3]=f0.w;
            f[c][4]=f1.x;  f[c][5]=f1.y;  f[c][6]=f1.z;  f[c][7]=f1.w;
            f[c][8]=f2.x;  f[c][9]=f2.y;  f[c][10]=f2.z; f[c][11]=f2.w;
            f[c][12]=f3.x; f[c][13]=f3.y; f[c][14]=f3.z; f[c][15]=f3.w;
        }

        // cv[j] for output x0+j lives at lds[row][x0+4+j] -> aligned b128 pair, row uniform
        const float4* cvp = reinterpret_cast<const float4*>(lds) + (tx * 2 + 1);
        #pragma unroll
        for (int kdx = 0; kdx < DD; ++kdx) {
            int row = kdy * DD + kdx;
            float4 ca = cvp[row * LW4];
            float4 cb = cvp[row * LW4 + 1];
            float cv[8] = {ca.x, ca.y, ca.z, ca.w, cb.x, cb.y, cb.z, cb.w};
            #pragma unroll
            for (int c = 0; c < CT; ++c)
                #pragma unroll
                for (int j = 0; j < TXR; ++j)
                    acc[c][j] = fmaf(cv[j], f[c][j + 8 - kdx], acc[c][j]);
        }
    }

    float* ob = out + ((size_t)b * Cn + c0) * HWn + (size_t)y * Wn + x0;
    #pragma unroll
    for (int c = 0; c < CT; ++c) {
        *reinterpret_cast<float4*>(ob + (size_t)c * HWn)     = make_float4(acc[c][0], acc[c][1], acc[c][2], acc[c][3]);
        *reinterpret_cast<float4*>(ob + (size_t)c * HWn + 4) = make_float4(acc[c][4], acc[c][5], acc[c][6], acc[c][7]);
    }
}

extern "C" void kernel_launch(void* const* d_in, const int* in_sizes, int n_in,
                              void* d_out, int out_size, void* d_ws, size_t ws_size,
                              hipStream_t stream)
{
    const float* corr = (const float*)d_in[0];   // [16,81,96,96]
    const float* feat = (const float*)d_in[1];   // [16,256,96,96]
    float* out = (float*)d_out;                  // [16,256,96,96]

    const int grid = Bn * Hn * NCG;              // 16*96*4 = 6144
    corrT3_kernel<<<grid, NTH, 0, stream>>>(corr, feat, out);
}